// Round 12
// baseline (3142.395 us; speedup 1.0000x reference)
//
#include <hip/hip_runtime.h>

#define Bn 8
#define Nn 8192
#define Cn 64
#define Mn 2048
#define Kn 16
#define FPS_T 512
#define PPT 16
#define NPAIR 8
#define NWAVE 8

typedef float f32x2 __attribute__((ext_vector_type(2)));
typedef unsigned long long u64;
typedef unsigned u32;

__device__ __forceinline__ u64 u64max(u64 a, u64 b) { return a > b ? a : b; }

// ---- DPP wave-64 reductions (validated r4-r10), result in lane 63.
template <int CTRL, int RMASK>
__device__ __forceinline__ float dpp_max_step(float v) {
    int mv = __builtin_amdgcn_update_dpp(__float_as_int(v), __float_as_int(v),
                                         CTRL, RMASK, 0xF, false);
    return fmaxf(v, __int_as_float(mv));
}
template <int CTRL, int RMASK>
__device__ __forceinline__ unsigned dpp_min_step(unsigned v) {
    unsigned mv = (unsigned)__builtin_amdgcn_update_dpp((int)v, (int)v,
                                                        CTRL, RMASK, 0xF, false);
    return (mv < v) ? mv : v;
}
__device__ __forceinline__ float wave_max_f32(float v) {
    v = dpp_max_step<0x111, 0xF>(v);
    v = dpp_max_step<0x112, 0xF>(v);
    v = dpp_max_step<0x114, 0xF>(v);
    v = dpp_max_step<0x118, 0xF>(v);
    v = dpp_max_step<0x142, 0xA>(v);
    v = dpp_max_step<0x143, 0xC>(v);
    return v;
}
__device__ __forceinline__ unsigned wave_min_u32(unsigned v) {
    v = dpp_min_step<0x111, 0xF>(v);
    v = dpp_min_step<0x112, 0xF>(v);
    v = dpp_min_step<0x114, 0xF>(v);
    v = dpp_min_step<0x118, 0xF>(v);
    v = dpp_min_step<0x142, 0xA>(v);
    v = dpp_min_step<0x143, 0xC>(v);
    return v;
}

// ---------------------------------------------------------------------------
// FPS. One block/batch, 512 threads (8 waves, 2/SIMD). Always-update (no
// skip/sort). Per iter: spin-sync on LDS generation counters (replaces
// __syncthreads), packed-FP32 register update (r6-validated asm), value-only
// DPP fmax reduce + first-index scan + DPP u32 min (r4-validated split),
// per-wave slot carries key + winner coords (r10-validated).
//
// Spin-sync safety: wave w writes slot[m&1][w] only after its spin saw all
// gens >= m; gen v>=m implies wave v finished its epoch-(m-1) select reads
// (which covered slot[(m-2)&1] == slot[m&1]) -- so no reader of the old
// contents remains. Writer orders slot data before gen via
// __threadfence_block. Gens zeroed before the single startup barrier, so
// graph replays are deterministic. Arithmetic bit-identical to XLA
// (separate rn mul/add, no FMA; pk ops are IEEE rn per-lane); argmax
// tie-break = smallest original index (u64 key V<<32 | ~g, validated).
// ---------------------------------------------------------------------------
__global__ __launch_bounds__(FPS_T) void fps_kernel(
    const float* __restrict__ p1,
    float* __restrict__ out_p2,
    float* __restrict__ out_idxf)
{
    __shared__ float s_Px[Nn], s_Py[Nn], s_Pz[Nn];   // 96 KB, original order
    __shared__ u32 s_osel[Mn];                        // 8 KB selected g
    __shared__ u32 s_slot[2][NWAVE][8];               // key+coords per wave
    __shared__ volatile u32 s_gen[NWAVE];

    const int b = blockIdx.x, t = threadIdx.x, w = t >> 6, lane = t & 63;
    const float* __restrict__ P = p1 + (size_t)b * (Nn * 3);

    f32x2 px2[NPAIR], py2[NPAIR], pz2[NPAIR], d2v[NPAIR];
#pragma unroll
    for (int j = 0; j < PPT; ++j) {
        const int g = t + j * FPS_T;
        const float x = P[g * 3 + 0];
        const float y = P[g * 3 + 1];
        const float z = P[g * 3 + 2];
        s_Px[g] = x; s_Py[g] = y; s_Pz[g] = z;
        const int k = j >> 1;
        if ((j & 1) == 0) { px2[k].x = x; py2[k].x = y; pz2[k].x = z; d2v[k].x = __int_as_float(0x7f800000); }
        else              { px2[k].y = x; py2[k].y = y; pz2[k].y = z; d2v[k].y = __int_as_float(0x7f800000); }
    }
    if (t < NWAVE) s_gen[t] = 0u;
    if (t == 0) s_osel[0] = 0u;
    __syncthreads();   // the only full barrier before the flush

    float qx = s_Px[0], qy = s_Py[0], qz = s_Pz[0];

    // ---- one epoch: exact update + wave argmax + slot publish ----
    auto step = [&](int buf, u32 gen) {
        const f32x2 nqx = { -qx, -qx };
        const f32x2 nqy = { -qy, -qy };
        const f32x2 nqz = { -qz, -qz };
        float lm = -1.0f;
#pragma unroll
        for (int k = 0; k < NPAIR; ++k) {
            f32x2 s, t1, t2;
            // dx=p+(-q); squares; (x^2+y^2)+z^2 -- rn each step, no FMA (r6-validated)
            asm("v_pk_add_f32 %0, %3, %6\n\t"
                "v_pk_add_f32 %1, %4, %7\n\t"
                "v_pk_add_f32 %2, %5, %8\n\t"
                "v_pk_mul_f32 %0, %0, %0\n\t"
                "v_pk_mul_f32 %1, %1, %1\n\t"
                "v_pk_mul_f32 %2, %2, %2\n\t"
                "v_pk_add_f32 %0, %0, %1\n\t"
                "v_pk_add_f32 %0, %0, %2"
                : "=&v"(s), "=&v"(t1), "=&v"(t2)
                : "v"(px2[k]), "v"(py2[k]), "v"(pz2[k]),
                  "v"(nqx), "v"(nqy), "v"(nqz));
            const float nlo = fminf(d2v[k].x, s.x);
            const float nhi = fminf(d2v[k].y, s.y);
            d2v[k].x = nlo; d2v[k].y = nhi;
            lm = fmaxf(lm, fmaxf(nlo, nhi));
        }
        const float wv = wave_max_f32(lm);
        const float V = __int_as_float(
            __builtin_amdgcn_readlane(__float_as_int(wv), 63));
        u32 cand = 0xFFFFFFFFu;
#pragma unroll
        for (int k = NPAIR - 1; k >= 0; --k) {       // descending g order
            const u32 ghi = (u32)(t + (2 * k + 1) * FPS_T);
            const u32 glo = (u32)(t + (2 * k) * FPS_T);
            cand = (d2v[k].y == V) ? ghi : cand;
            cand = (d2v[k].x == V) ? glo : cand;
        }
        cand = wave_min_u32(cand);                    // lane63: first idx at V
        if (lane == 63) {
            const u32 g = cand;
            u32* sl = (u32*)&s_slot[buf][w][0];
            sl[0] = __float_as_uint(V);
            sl[1] = (~g) & 0x1FFFu;
            sl[2] = __float_as_uint(s_Px[g]);
            sl[3] = __float_as_uint(s_Py[g]);
            sl[4] = __float_as_uint(s_Pz[g]);
            __threadfence_block();                    // slot data before gen
            s_gen[w] = gen;
        }
    };

    step(0, 1u);   // epoch 0 with q0

    for (int m = 1; m < Mn; ++m) {
        // ---- spin until every wave has published epoch m-1 ----
        for (;;) {
            u32 mn = s_gen[0];
#pragma unroll
            for (int i = 1; i < NWAVE; ++i) {
                const u32 v = s_gen[i];
                mn = v < mn ? v : mn;
            }
            if (mn >= (u32)m) break;
        }
        asm volatile("" ::: "memory");   // no hoisting of slot reads above spin

        const int rb = (m - 1) & 1;
        u64 K[NWAVE]; float Qx[NWAVE], Qy[NWAVE], Qz[NWAVE];
#pragma unroll
        for (int i = 0; i < NWAVE; ++i) {
            const u32* sl = (const u32*)&s_slot[rb][i][0];
            K[i]  = ((u64)sl[0] << 32) | sl[1];
            Qx[i] = __uint_as_float(sl[2]);
            Qy[i] = __uint_as_float(sl[3]);
            Qz[i] = __uint_as_float(sl[4]);
        }
        u64 kk = K[0];
#pragma unroll
        for (int i = 1; i < NWAVE; ++i) kk = u64max(kk, K[i]);
        qx = Qx[0]; qy = Qy[0]; qz = Qz[0];
#pragma unroll
        for (int i = 1; i < NWAVE; ++i) {
            const bool win = (K[i] == kk);
            qx = win ? Qx[i] : qx;
            qy = win ? Qy[i] : qy;
            qz = win ? Qz[i] : qz;
        }
        if (t == 0) s_osel[m] = (~(u32)kk) & 0x1FFFu;

        step(m & 1, (u32)(m + 1));
    }
    __syncthreads();

    // ---- flush outputs ----
    float* __restrict__ o2 = out_p2 + (size_t)b * Mn * 3;
    float* __restrict__ oi = out_idxf + (size_t)b * Mn;
    for (int i = t; i < Mn; i += FPS_T) {
        const u32 g = s_osel[i];
        oi[i] = (float)g;
        o2[i * 3 + 0] = s_Px[g];
        o2[i * 3 + 1] = s_Py[g];
        o2[i * 3 + 2] = s_Pz[g];
    }
}

// ---------------------------------------------------------------------------
// kNN + feature mean (unchanged -- passed rounds 1/4/5/6/7/9/10).
// ---------------------------------------------------------------------------
#define KNN_WPB 4
__global__ __launch_bounds__(64 * KNN_WPB) void knn_mean_kernel(
    const float* __restrict__ p1,
    const float* __restrict__ x,
    const float* __restrict__ p2,
    float* __restrict__ y)
{
    const int lane = threadIdx.x & 63;
    const int wid  = threadIdx.x >> 6;
    const int q    = blockIdx.x * KNN_WPB + wid;    // 0 .. B*M-1
    const int b    = q >> 11;                        // q / Mn  (Mn = 2048)
    const float* __restrict__ P = p1 + (size_t)b * (Nn * 3);

    const float qx = p2[(size_t)q * 3 + 0];
    const float qy = p2[(size_t)q * 3 + 1];
    const float qz = p2[(size_t)q * 3 + 2];
    const float qq = __fadd_rn(
        __fadd_rn(__fmul_rn(qx, qx), __fmul_rn(qy, qy)), __fmul_rn(qz, qz));

    float slotv = __int_as_float(0x7f800000);
    int   sloti = 0x7fffffff;
    float thr   = __int_as_float(0x7f800000);
    int   thri  = 0x7fffffff;

    for (int c = 0; c < Nn / 64; ++c) {
        const int g = c * 64 + lane;
        const float ax = P[g * 3 + 0];
        const float ay = P[g * 3 + 1];
        const float az = P[g * 3 + 2];
        const float pp = __fadd_rn(
            __fadd_rn(__fmul_rn(ax, ax), __fmul_rn(ay, ay)), __fmul_rn(az, az));
        const float dot = __fmaf_rn(az, qz, __fmaf_rn(ay, qy, __fmul_rn(ax, qx)));
        const float d = __fsub_rn(__fadd_rn(qq, pp), __fmul_rn(2.0f, dot));
        const bool pass = (d < thr) || (d == thr && g < thri);
        unsigned long long ball = __ballot(pass);
        while (ball) {
            const int src = __builtin_ctzll(ball);
            ball &= ball - 1ull;
            const float v  = __shfl(d, src);
            const int   vi = __shfl(g, src);
            const float upv = __shfl_up(slotv, 1);
            const int   upi = __shfl_up(sloti, 1);
            const bool beforeme = (v < slotv) || (v == slotv && vi < sloti);
            bool beforeup = (v < upv) || (v == upv && vi < upi);
            if (lane == 0) beforeup = false;
            if (beforeme) {
                slotv = beforeup ? upv : v;
                sloti = beforeup ? upi : vi;
            }
            thr  = __shfl(slotv, 15);
            thri = __shfl(sloti, 15);
        }
    }

    float acc = 0.0f;
    const float* __restrict__ xb = x + (size_t)b * Nn * Cn;
#pragma unroll
    for (int s = 0; s < Kn; ++s) {
        const int ni = __shfl(sloti, s);
        acc = __fadd_rn(acc, xb[(size_t)ni * Cn + lane]);   // lane == channel
    }
    y[(size_t)q * Cn + lane] = __fmul_rn(acc, 0.0625f);
}

// ---------------------------------------------------------------------------
extern "C" void kernel_launch(void* const* d_in, const int* in_sizes, int n_in,
                              void* d_out, int out_size, void* d_ws, size_t ws_size,
                              hipStream_t stream) {
    const float* p1 = (const float*)d_in[0];
    const float* x  = (const float*)d_in[1];

    float* y    = (float*)d_out;                       // (B, M, C)
    float* p2   = y    + (size_t)Bn * Mn * Cn;         // (B, M, 3)
    float* idxf = p2   + (size_t)Bn * Mn * 3;          // (B, M) as float

    fps_kernel<<<Bn, FPS_T, 0, stream>>>(p1, p2, idxf);
    knn_mean_kernel<<<(Bn * Mn) / KNN_WPB, 64 * KNN_WPB, 0, stream>>>(p1, x, p2, y);
}

// Round 13
// 2790.649 us; speedup vs baseline: 1.1260x; 1.1260x over previous
//
#include <hip/hip_runtime.h>

#define Bn 8
#define Nn 8192
#define Cn 64
#define Mn 2048
#define Kn 16
#define FPS_T 512
#define PPT 16
#define NPAIR 8
#define NWAVE 8

typedef float f32x2 __attribute__((ext_vector_type(2)));
typedef unsigned long long u64;
typedef unsigned u32;

__device__ __forceinline__ u64 u64max(u64 a, u64 b) { return a > b ? a : b; }

// ---- DPP wave-64 reductions (validated r4-r12), result in lane 63.
template <int CTRL, int RMASK>
__device__ __forceinline__ float dpp_max_step(float v) {
    int mv = __builtin_amdgcn_update_dpp(__float_as_int(v), __float_as_int(v),
                                         CTRL, RMASK, 0xF, false);
    return fmaxf(v, __int_as_float(mv));
}
template <int CTRL, int RMASK>
__device__ __forceinline__ unsigned dpp_min_step(unsigned v) {
    unsigned mv = (unsigned)__builtin_amdgcn_update_dpp((int)v, (int)v,
                                                        CTRL, RMASK, 0xF, false);
    return (mv < v) ? mv : v;
}
__device__ __forceinline__ float wave_max_f32(float v) {
    v = dpp_max_step<0x111, 0xF>(v);
    v = dpp_max_step<0x112, 0xF>(v);
    v = dpp_max_step<0x114, 0xF>(v);
    v = dpp_max_step<0x118, 0xF>(v);
    v = dpp_max_step<0x142, 0xA>(v);
    v = dpp_max_step<0x143, 0xC>(v);
    return v;
}
__device__ __forceinline__ unsigned wave_min_u32(unsigned v) {
    v = dpp_min_step<0x111, 0xF>(v);
    v = dpp_min_step<0x112, 0xF>(v);
    v = dpp_min_step<0x114, 0xF>(v);
    v = dpp_min_step<0x118, 0xF>(v);
    v = dpp_min_step<0x142, 0xA>(v);
    v = dpp_min_step<0x143, 0xC>(v);
    return v;
}

// ---------------------------------------------------------------------------
// FPS. r4 structure (best so far: 512T, 8 waves, one __syncthreads/iter,
// always-update) + two isolated trims:
//   (1) packed dual-FP32 update via inline-asm VOP3P (r6 asm, now at
//       2 waves/SIMD): per-lane rn semantics identical to scalar ops.
//   (2) per-wave slots carry winner coords (r10/r11-validated), removing the
//       dependent post-barrier s_Px[bi] read.
// Selection semantics bit-identical to XLA: separate rn mul/add (no FMA),
// argmax = max value then smallest original index (u64 key V<<32 | ~g).
// ---------------------------------------------------------------------------
__global__ __launch_bounds__(FPS_T) void fps_kernel(
    const float* __restrict__ p1,
    float* __restrict__ out_p2,
    float* __restrict__ out_idxf)
{
    __shared__ float s_Px[Nn], s_Py[Nn], s_Pz[Nn];   // 96 KB, original order
    __shared__ u32 s_osel[Mn];                        // 8 KB selected g
    __shared__ u32 s_slot[2][NWAVE][8];               // key + coords per wave
    __shared__ u32 s_gpad;                            // (unused filler)

    const int b = blockIdx.x, t = threadIdx.x, w = t >> 6, lane = t & 63;
    const float* __restrict__ P = p1 + (size_t)b * (Nn * 3);

    f32x2 px2[NPAIR], py2[NPAIR], pz2[NPAIR], d2v[NPAIR];
#pragma unroll
    for (int j = 0; j < PPT; ++j) {
        const int g = t + j * FPS_T;
        const float x = P[g * 3 + 0];
        const float y = P[g * 3 + 1];
        const float z = P[g * 3 + 2];
        s_Px[g] = x; s_Py[g] = y; s_Pz[g] = z;
        const int k = j >> 1;
        if ((j & 1) == 0) { px2[k].x = x; py2[k].x = y; pz2[k].x = z; d2v[k].x = __int_as_float(0x7f800000); }
        else              { px2[k].y = x; py2[k].y = y; pz2[k].y = z; d2v[k].y = __int_as_float(0x7f800000); }
    }
    if (t == 0) s_osel[0] = 0u;
    __syncthreads();

    float qx = s_Px[0], qy = s_Py[0], qz = s_Pz[0];

    // ---- one epoch: packed exact update + wave argmax + slot publish ----
    auto step = [&](int buf) {
        const f32x2 nqx = { -qx, -qx };
        const f32x2 nqy = { -qy, -qy };
        const f32x2 nqz = { -qz, -qz };
        float lm = -1.0f;
#pragma unroll
        for (int k = 0; k < NPAIR; ++k) {
            f32x2 s, t1, t2;
            // dx=p+(-q); squares; (x^2+y^2)+z^2 -- rn each step, no FMA.
            asm("v_pk_add_f32 %0, %3, %6\n\t"
                "v_pk_add_f32 %1, %4, %7\n\t"
                "v_pk_add_f32 %2, %5, %8\n\t"
                "v_pk_mul_f32 %0, %0, %0\n\t"
                "v_pk_mul_f32 %1, %1, %1\n\t"
                "v_pk_mul_f32 %2, %2, %2\n\t"
                "v_pk_add_f32 %0, %0, %1\n\t"
                "v_pk_add_f32 %0, %0, %2"
                : "=&v"(s), "=&v"(t1), "=&v"(t2)
                : "v"(px2[k]), "v"(py2[k]), "v"(pz2[k]),
                  "v"(nqx), "v"(nqy), "v"(nqz));
            const float nlo = fminf(d2v[k].x, s.x);
            const float nhi = fminf(d2v[k].y, s.y);
            d2v[k].x = nlo; d2v[k].y = nhi;
            lm = fmaxf(lm, fmaxf(nlo, nhi));   // -> v_max3
        }
        const float wv = wave_max_f32(lm);
        const float V = __int_as_float(
            __builtin_amdgcn_readlane(__float_as_int(wv), 63));
        u32 cand = 0xFFFFFFFFu;
#pragma unroll
        for (int k = NPAIR - 1; k >= 0; --k) {       // descending g order
            const u32 ghi = (u32)(t + (2 * k + 1) * FPS_T);
            const u32 glo = (u32)(t + (2 * k) * FPS_T);
            cand = (d2v[k].y == V) ? ghi : cand;
            cand = (d2v[k].x == V) ? glo : cand;
        }
        cand = wave_min_u32(cand);                    // lane63: first idx at V
        if (lane == 63) {
            const u32 g = cand;
            u32* sl = (u32*)&s_slot[buf][w][0];
            sl[0] = __float_as_uint(V);
            sl[1] = (~g) & 0x1FFFu;
            sl[2] = __float_as_uint(s_Px[g]);
            sl[3] = __float_as_uint(s_Py[g]);
            sl[4] = __float_as_uint(s_Pz[g]);
        }
    };

    step(0);   // epoch 0 with q0
    __syncthreads();

    for (int m = 1; m < Mn; ++m) {
        // ---- select sample m from previous epoch's slots ----
        const int rb = (m - 1) & 1;
        u64 K[NWAVE]; float Qx[NWAVE], Qy[NWAVE], Qz[NWAVE];
#pragma unroll
        for (int i = 0; i < NWAVE; ++i) {
            const u32* sl = (const u32*)&s_slot[rb][i][0];
            K[i]  = ((u64)sl[0] << 32) | sl[1];
            Qx[i] = __uint_as_float(sl[2]);
            Qy[i] = __uint_as_float(sl[3]);
            Qz[i] = __uint_as_float(sl[4]);
        }
        u64 kk = K[0];
#pragma unroll
        for (int i = 1; i < NWAVE; ++i) kk = u64max(kk, K[i]);
        qx = Qx[0]; qy = Qy[0]; qz = Qz[0];
#pragma unroll
        for (int i = 1; i < NWAVE; ++i) {
            const bool win = (K[i] == kk);
            qx = win ? Qx[i] : qx;
            qy = win ? Qy[i] : qy;
            qz = win ? Qz[i] : qz;
        }
        if (t == 0) s_osel[m] = (~(u32)kk) & 0x1FFFu;

        step(m & 1);
        __syncthreads();
    }

    // ---- flush outputs ----
    float* __restrict__ o2 = out_p2 + (size_t)b * Mn * 3;
    float* __restrict__ oi = out_idxf + (size_t)b * Mn;
    for (int i = t; i < Mn; i += FPS_T) {
        const u32 g = s_osel[i];
        oi[i] = (float)g;
        o2[i * 3 + 0] = s_Px[g];
        o2[i * 3 + 1] = s_Py[g];
        o2[i * 3 + 2] = s_Pz[g];
    }
}

// ---------------------------------------------------------------------------
// kNN + feature mean (unchanged -- passed rounds 1/4/5/6/7/9/10/12).
// ---------------------------------------------------------------------------
#define KNN_WPB 4
__global__ __launch_bounds__(64 * KNN_WPB) void knn_mean_kernel(
    const float* __restrict__ p1,
    const float* __restrict__ x,
    const float* __restrict__ p2,
    float* __restrict__ y)
{
    const int lane = threadIdx.x & 63;
    const int wid  = threadIdx.x >> 6;
    const int q    = blockIdx.x * KNN_WPB + wid;    // 0 .. B*M-1
    const int b    = q >> 11;                        // q / Mn  (Mn = 2048)
    const float* __restrict__ P = p1 + (size_t)b * (Nn * 3);

    const float qx = p2[(size_t)q * 3 + 0];
    const float qy = p2[(size_t)q * 3 + 1];
    const float qz = p2[(size_t)q * 3 + 2];
    const float qq = __fadd_rn(
        __fadd_rn(__fmul_rn(qx, qx), __fmul_rn(qy, qy)), __fmul_rn(qz, qz));

    float slotv = __int_as_float(0x7f800000);
    int   sloti = 0x7fffffff;
    float thr   = __int_as_float(0x7f800000);
    int   thri  = 0x7fffffff;

    for (int c = 0; c < Nn / 64; ++c) {
        const int g = c * 64 + lane;
        const float ax = P[g * 3 + 0];
        const float ay = P[g * 3 + 1];
        const float az = P[g * 3 + 2];
        const float pp = __fadd_rn(
            __fadd_rn(__fmul_rn(ax, ax), __fmul_rn(ay, ay)), __fmul_rn(az, az));
        const float dot = __fmaf_rn(az, qz, __fmaf_rn(ay, qy, __fmul_rn(ax, qx)));
        const float d = __fsub_rn(__fadd_rn(qq, pp), __fmul_rn(2.0f, dot));
        const bool pass = (d < thr) || (d == thr && g < thri);
        unsigned long long ball = __ballot(pass);
        while (ball) {
            const int src = __builtin_ctzll(ball);
            ball &= ball - 1ull;
            const float v  = __shfl(d, src);
            const int   vi = __shfl(g, src);
            const float upv = __shfl_up(slotv, 1);
            const int   upi = __shfl_up(sloti, 1);
            const bool beforeme = (v < slotv) || (v == slotv && vi < sloti);
            bool beforeup = (v < upv) || (v == upv && vi < upi);
            if (lane == 0) beforeup = false;
            if (beforeme) {
                slotv = beforeup ? upv : v;
                sloti = beforeup ? upi : vi;
            }
            thr  = __shfl(slotv, 15);
            thri = __shfl(sloti, 15);
        }
    }

    float acc = 0.0f;
    const float* __restrict__ xb = x + (size_t)b * Nn * Cn;
#pragma unroll
    for (int s = 0; s < Kn; ++s) {
        const int ni = __shfl(sloti, s);
        acc = __fadd_rn(acc, xb[(size_t)ni * Cn + lane]);   // lane == channel
    }
    y[(size_t)q * Cn + lane] = __fmul_rn(acc, 0.0625f);
}

// ---------------------------------------------------------------------------
extern "C" void kernel_launch(void* const* d_in, const int* in_sizes, int n_in,
                              void* d_out, int out_size, void* d_ws, size_t ws_size,
                              hipStream_t stream) {
    const float* p1 = (const float*)d_in[0];
    const float* x  = (const float*)d_in[1];

    float* y    = (float*)d_out;                       // (B, M, C)
    float* p2   = y    + (size_t)Bn * Mn * Cn;         // (B, M, 3)
    float* idxf = p2   + (size_t)Bn * Mn * 3;          // (B, M) as float

    fps_kernel<<<Bn, FPS_T, 0, stream>>>(p1, p2, idxf);
    knn_mean_kernel<<<(Bn * Mn) / KNN_WPB, 64 * KNN_WPB, 0, stream>>>(p1, x, p2, y);
}

// Round 14
// 2507.828 us; speedup vs baseline: 1.2530x; 1.1128x over previous
//
#include <hip/hip_runtime.h>

#define Bn 8
#define Nn 8192
#define Cn 64
#define Mn 2048
#define Kn 16
#define FPS_T 512
#define PPT (Nn / FPS_T)     // 16 points/thread
#define NPAIR (PPT / 2)      // 8 float2 pairs/thread

typedef float f32x2 __attribute__((ext_vector_type(2)));
typedef unsigned long long u64;

// ---- DPP wave-64 reductions (validated r4-r13), result valid in lane 63.
template <int CTRL, int RMASK>
__device__ __forceinline__ float dpp_max_step(float v) {
    int mv = __builtin_amdgcn_update_dpp(__float_as_int(v), __float_as_int(v),
                                         CTRL, RMASK, 0xF, false);
    return fmaxf(v, __int_as_float(mv));
}
template <int CTRL, int RMASK>
__device__ __forceinline__ unsigned dpp_min_step(unsigned v) {
    unsigned mv = (unsigned)__builtin_amdgcn_update_dpp((int)v, (int)v,
                                                        CTRL, RMASK, 0xF, false);
    return (mv < v) ? mv : v;
}
__device__ __forceinline__ float wave_max_f32(float v) {
    v = dpp_max_step<0x111, 0xF>(v);   // row_shr:1
    v = dpp_max_step<0x112, 0xF>(v);   // row_shr:2
    v = dpp_max_step<0x114, 0xF>(v);   // row_shr:4
    v = dpp_max_step<0x118, 0xF>(v);   // row_shr:8
    v = dpp_max_step<0x142, 0xA>(v);   // row_bcast:15
    v = dpp_max_step<0x143, 0xC>(v);   // row_bcast:31
    return v;
}
__device__ __forceinline__ unsigned wave_min_u32(unsigned v) {
    v = dpp_min_step<0x111, 0xF>(v);
    v = dpp_min_step<0x112, 0xF>(v);
    v = dpp_min_step<0x114, 0xF>(v);
    v = dpp_min_step<0x118, 0xF>(v);
    v = dpp_min_step<0x142, 0xA>(v);
    v = dpp_min_step<0x143, 0xC>(v);
    return v;
}
__device__ __forceinline__ u64 u64max(u64 a, u64 b) { return a > b ? a : b; }

// ---------------------------------------------------------------------------
// ABLATION BUILD: r5 kernel (best, 1913 us) with the distance-update phase
// executed TWICE per iteration. Pass 1 (dist+min only) is idempotent --
// min(min(d2,dist),dist) == min(d2,dist) and q is unchanged -- so output is
// bit-identical to the base kernel. The empty asm on q between passes defeats
// value-numbering/DCE, forcing pass 1 to be fully emitted. The measured
// dur delta vs 1913 us isolates the marginal cost of one update pass.
// ---------------------------------------------------------------------------
__global__ __launch_bounds__(FPS_T) void fps_kernel(
    const float* __restrict__ p1,
    float* __restrict__ out_p2,
    float* __restrict__ out_idxf)
{
#pragma clang fp contract(off)
    __shared__ float s_Px[Nn], s_Py[Nn], s_Pz[Nn];      // 96 KB
    __shared__ u64 s_wkey[2][8];
    __shared__ int s_oidx[Mn];                           // 8 KB

    const int b = blockIdx.x;
    const int t = threadIdx.x;
    const int w = t >> 6;
    const float* __restrict__ P = p1 + (size_t)b * (Nn * 3);

    f32x2 px2[NPAIR], py2[NPAIR], pz2[NPAIR], d2v[NPAIR];
#pragma unroll
    for (int j = 0; j < PPT; ++j) {
        const int g = t + j * FPS_T;
        const float x = P[g * 3 + 0];
        const float y = P[g * 3 + 1];
        const float z = P[g * 3 + 2];
        const int k = j >> 1;
        if ((j & 1) == 0) { px2[k].x = x; py2[k].x = y; pz2[k].x = z; d2v[k].x = __int_as_float(0x7f800000); }
        else              { px2[k].y = x; py2[k].y = y; pz2[k].y = z; d2v[k].y = __int_as_float(0x7f800000); }
        s_Px[g] = x; s_Py[g] = y; s_Pz[g] = z;
    }
    if (t == 0) s_oidx[0] = 0;
    __syncthreads();

    float qx = s_Px[0], qy = s_Py[0], qz = s_Pz[0];

    for (int m = 1; m < Mn; ++m) {
#pragma clang fp contract(off)
        // ---- ABLATION PASS 1: idempotent pre-update (dist + min only) ----
        {
            const f32x2 nqx = { -qx, -qx };
            const f32x2 nqy = { -qy, -qy };
            const f32x2 nqz = { -qz, -qz };
#pragma unroll
            for (int k = 0; k < NPAIR; ++k) {
                const f32x2 dx = px2[k] + nqx;
                const f32x2 dy = py2[k] + nqy;
                const f32x2 dz = pz2[k] + nqz;
                const f32x2 mx = dx * dx;
                const f32x2 my = dy * dy;
                const f32x2 mz = dz * dz;
                const f32x2 s  = (mx + my) + mz;
                d2v[k].x = fminf(d2v[k].x, s.x);
                d2v[k].y = fminf(d2v[k].y, s.y);
            }
        }
        // Defeat CSE/DCE: q appears modified (values unchanged).
        asm volatile("" : "+v"(qx), "+v"(qy), "+v"(qz));

        // ---- REAL update (identical to base kernel) ----
        const f32x2 nqx = { -qx, -qx };
        const f32x2 nqy = { -qy, -qy };
        const f32x2 nqz = { -qz, -qz };
        float lm = -1.0f;
#pragma unroll
        for (int k = 0; k < NPAIR; ++k) {
            const f32x2 dx = px2[k] + nqx;            // p - q  (exact: x+(-y))
            const f32x2 dy = py2[k] + nqy;
            const f32x2 dz = pz2[k] + nqz;
            const f32x2 mx = dx * dx;
            const f32x2 my = dy * dy;
            const f32x2 mz = dz * dz;
            const f32x2 s  = (mx + my) + mz;          // XLA order, no FMA
            const float nlo = fminf(d2v[k].x, s.x);
            const float nhi = fminf(d2v[k].y, s.y);
            d2v[k].x = nlo;
            d2v[k].y = nhi;
            lm = fmaxf(lm, nlo);
            lm = fmaxf(lm, nhi);
        }
        // ---- wave max value ----
        lm = wave_max_f32(lm);
        const float V = __int_as_float(
            __builtin_amdgcn_readlane(__float_as_int(lm), 63));
        // ---- first (smallest) global index in this thread matching V ----
        unsigned cand = 0xFFFFFFFFu;
#pragma unroll
        for (int k = NPAIR - 1; k >= 0; --k) {        // descending g order
            const unsigned ghi = (unsigned)(t + (2 * k + 1) * FPS_T);
            const unsigned glo = (unsigned)(t + (2 * k) * FPS_T);
            cand = (d2v[k].y == V) ? ghi : cand;
            cand = (d2v[k].x == V) ? glo : cand;
        }
        // ---- wave min index ----
        cand = wave_min_u32(cand);
        // ---- publish per-wave key; double-buffered slots, one barrier ----
        if ((t & 63) == 63) {
            const u64 key = ((u64)(unsigned)__float_as_int(V) << 32) |
                            (u64)(~cand);
            s_wkey[m & 1][w] = key;
        }
        __syncthreads();
        const u64* __restrict__ K = s_wkey[m & 1];
        const u64 a0 = u64max(K[0], K[1]);
        const u64 a1 = u64max(K[2], K[3]);
        const u64 a2 = u64max(K[4], K[5]);
        const u64 a3 = u64max(K[6], K[7]);
        const u64 kk = u64max(u64max(a0, a1), u64max(a2, a3));
        const int bi = (int)(~(unsigned)kk);
        if (t == 0) s_oidx[m] = bi;
        qx = s_Px[bi]; qy = s_Py[bi]; qz = s_Pz[bi];   // broadcast LDS reads
    }
    __syncthreads();

    // ---- flush outputs ----
    float* __restrict__ o2 = out_p2 + (size_t)b * Mn * 3;
    float* __restrict__ oi = out_idxf + (size_t)b * Mn;
    for (int i = t; i < Mn; i += FPS_T) {
        const int bi = s_oidx[i];
        oi[i] = (float)bi;
        o2[i * 3 + 0] = s_Px[bi];
        o2[i * 3 + 1] = s_Py[bi];
        o2[i * 3 + 2] = s_Pz[bi];
    }
}

// ---------------------------------------------------------------------------
// kNN + feature mean (unchanged -- passed rounds 1/4/5/6/7/9/10/12/13).
// ---------------------------------------------------------------------------
#define KNN_WPB 4
__global__ __launch_bounds__(64 * KNN_WPB) void knn_mean_kernel(
    const float* __restrict__ p1,
    const float* __restrict__ x,
    const float* __restrict__ p2,
    float* __restrict__ y)
{
    const int lane = threadIdx.x & 63;
    const int wid  = threadIdx.x >> 6;
    const int q    = blockIdx.x * KNN_WPB + wid;    // 0 .. B*M-1
    const int b    = q >> 11;                        // q / Mn  (Mn = 2048)
    const float* __restrict__ P = p1 + (size_t)b * (Nn * 3);

    const float qx = p2[(size_t)q * 3 + 0];
    const float qy = p2[(size_t)q * 3 + 1];
    const float qz = p2[(size_t)q * 3 + 2];
    const float qq = __fadd_rn(
        __fadd_rn(__fmul_rn(qx, qx), __fmul_rn(qy, qy)), __fmul_rn(qz, qz));

    float slotv = __int_as_float(0x7f800000);
    int   sloti = 0x7fffffff;
    float thr   = __int_as_float(0x7f800000);
    int   thri  = 0x7fffffff;

    for (int c = 0; c < Nn / 64; ++c) {
        const int g = c * 64 + lane;
        const float ax = P[g * 3 + 0];
        const float ay = P[g * 3 + 1];
        const float az = P[g * 3 + 2];
        const float pp = __fadd_rn(
            __fadd_rn(__fmul_rn(ax, ax), __fmul_rn(ay, ay)), __fmul_rn(az, az));
        const float dot = __fmaf_rn(az, qz, __fmaf_rn(ay, qy, __fmul_rn(ax, qx)));
        const float d = __fsub_rn(__fadd_rn(qq, pp), __fmul_rn(2.0f, dot));
        const bool pass = (d < thr) || (d == thr && g < thri);
        unsigned long long ball = __ballot(pass);
        while (ball) {
            const int src = __builtin_ctzll(ball);
            ball &= ball - 1ull;
            const float v  = __shfl(d, src);
            const int   vi = __shfl(g, src);
            const float upv = __shfl_up(slotv, 1);
            const int   upi = __shfl_up(sloti, 1);
            const bool beforeme = (v < slotv) || (v == slotv && vi < sloti);
            bool beforeup = (v < upv) || (v == upv && vi < upi);
            if (lane == 0) beforeup = false;
            if (beforeme) {
                slotv = beforeup ? upv : v;
                sloti = beforeup ? upi : vi;
            }
            thr  = __shfl(slotv, 15);
            thri = __shfl(sloti, 15);
        }
    }

    float acc = 0.0f;
    const float* __restrict__ xb = x + (size_t)b * Nn * Cn;
#pragma unroll
    for (int s = 0; s < Kn; ++s) {
        const int ni = __shfl(sloti, s);
        acc = __fadd_rn(acc, xb[(size_t)ni * Cn + lane]);   // lane == channel
    }
    y[(size_t)q * Cn + lane] = __fmul_rn(acc, 0.0625f);
}

// ---------------------------------------------------------------------------
extern "C" void kernel_launch(void* const* d_in, const int* in_sizes, int n_in,
                              void* d_out, int out_size, void* d_ws, size_t ws_size,
                              hipStream_t stream) {
    const float* p1 = (const float*)d_in[0];
    const float* x  = (const float*)d_in[1];

    float* y    = (float*)d_out;                       // (B, M, C)
    float* p2   = y    + (size_t)Bn * Mn * Cn;         // (B, M, 3)
    float* idxf = p2   + (size_t)Bn * Mn * 3;          // (B, M) as float

    fps_kernel<<<Bn, FPS_T, 0, stream>>>(p1, p2, idxf);
    knn_mean_kernel<<<(Bn * Mn) / KNN_WPB, 64 * KNN_WPB, 0, stream>>>(p1, x, p2, y);
}